// Round 15
// baseline (1081.735 us; speedup 1.0000x reference)
//
#include <hip/hip_runtime.h>
#include <hip/hip_bf16.h>
#include <stdint.h>

#define BB 16
#define TT 256
#define HH 256
#define EE 256
#define GG 1024      // 4*H
#define VV 50257
#define NN 4096      // B*T

typedef unsigned short u16;
typedef __attribute__((ext_vector_type(8))) short short8;
typedef __attribute__((ext_vector_type(4))) float f32x4;

__device__ __forceinline__ float sigm(float x){
    float e = __builtin_amdgcn_exp2f(fminf(-x*1.44269504f, 60.0f));
    return 1.0f/(1.0f+e);
}
__device__ __forceinline__ float tanha(float x){
    float e = __builtin_amdgcn_exp2f(fminf(x*2.885390082f, 60.0f));
    return (e-1.0f)/(e+1.0f);
}
__device__ __forceinline__ u16 f2bf(float f){
    uint32_t u = __float_as_uint(f);
    u = (u + 0x7FFFu + ((u>>16)&1u)) >> 16;
    return (u16)u;
}
// agent-scope (device-coherent) ops; data-as-flag polling. Sentinel bf16 = 0xFFFF (NaN, never produced).
__device__ __forceinline__ void st32_coh(uint32_t* p, uint32_t v){
    __hip_atomic_store(p, v, __ATOMIC_RELAXED, __HIP_MEMORY_SCOPE_AGENT);
}
__device__ __forceinline__ uint32_t poll_pair(const uint32_t* p){
    uint32_t v = __hip_atomic_load(p, __ATOMIC_RELAXED, __HIP_MEMORY_SCOPE_AGENT);
    while ((v & 0xFFFFu) == 0xFFFFu || (v >> 16) == 0xFFFFu){
        __builtin_amdgcn_s_sleep(1);
        v = __hip_atomic_load(p, __ATOMIC_RELAXED, __HIP_MEMORY_SCOPE_AGENT);
    }
    return v;
}
__device__ __forceinline__ void gl_lds16(const void* g, void* s){
    __builtin_amdgcn_global_load_lds((const __attribute__((address_space(1))) unsigned int*)g,
                                     (__attribute__((address_space(3))) unsigned int*)s, 16, 0, 0);
}

// ---------------- G1t[(t*16+b)][g] = b1[g] + sum_e emb[tok[b*T+t]][e] * W1[e][g]
__global__ __launch_bounds__(256) void g1_kernel(const int* __restrict__ tok, const float* __restrict__ emb,
                                                 const float* __restrict__ W1, const float* __restrict__ b1,
                                                 float* __restrict__ G1t){
    __shared__ float xs[64*64];
    __shared__ float wsm[64*64];
    int n0 = blockIdx.x * 64;
    int g0 = blockIdx.y * 64;
    int tid = threadIdx.x;
    int sl = tid & 63;
    int kk = (tid >> 6) * 16;
    int mytok = tok[n0 + sl];
    float acc[4][4] = {};
    int ni = tid & 15, gi = tid >> 4;
    for (int kc = 0; kc < 4; ++kc){
        int k0 = kc*64;
        __syncthreads();
        #pragma unroll
        for (int i4 = 0; i4 < 4; ++i4){
            float4 xv = *(const float4*)(&emb[(size_t)mytok*EE + k0 + kk + i4*4]);
            xs[(kk+i4*4+0)*64 + sl] = xv.x;
            xs[(kk+i4*4+1)*64 + sl] = xv.y;
            xs[(kk+i4*4+2)*64 + sl] = xv.z;
            xs[(kk+i4*4+3)*64 + sl] = xv.w;
        }
        #pragma unroll
        for (int i = 0; i < 16; ++i){
            wsm[(kk+i)*64 + sl] = W1[(size_t)(k0+kk+i)*GG + g0 + sl];
        }
        __syncthreads();
        for (int k = 0; k < 64; ++k){
            float4 av = *(const float4*)(&xs[k*64 + ni*4]);
            float4 bv = *(const float4*)(&wsm[k*64 + gi*4]);
            float a_[4] = {av.x, av.y, av.z, av.w};
            float b_[4] = {bv.x, bv.y, bv.z, bv.w};
            #pragma unroll
            for (int i = 0; i < 4; ++i)
                #pragma unroll
                for (int j = 0; j < 4; ++j)
                    acc[i][j] += a_[i]*b_[j];
        }
    }
    #pragma unroll
    for (int i = 0; i < 4; ++i){
        int n = n0 + ni*4 + i;
        int b = n >> 8;
        int tt_ = n & 255;
        float4 o;
        o.x = acc[i][0] + b1[g0+gi*4+0];
        o.y = acc[i][1] + b1[g0+gi*4+1];
        o.z = acc[i][2] + b1[g0+gi*4+2];
        o.w = acc[i][3] + b1[g0+gi*4+3];
        *(float4*)(&G1t[(size_t)(tt_*16 + b)*GG + g0 + gi*4]) = o;
    }
}

// ---------------- persistent: 64 recurrence blocks (8 groups x (4 L1 + 4 L2)), 160 transpose workers
// wave-autonomous act: wave owns 4 gates x 4 units (per-lane colg), act via in-wave __shfl
// h1y: [T][8grp][2b][128pair] u32 exchange (sentinel 0xFFFF); h2b: [16b][T][128pair] (= out_gemm A)
__global__ __launch_bounds__(1024) void persist_kernel(
        const float* __restrict__ G1t, const float* __restrict__ W1,
        const float* __restrict__ W2, const float* __restrict__ b2,
        const float* __restrict__ Wout, u16* __restrict__ WoutT,
        u16* __restrict__ h1y, u16* __restrict__ h2b){
    __shared__ __align__(16) char smem[12288];
    const int bid = blockIdx.x;
    const int tid = threadIdx.x;

    if (bid >= 64){
        // ---- Wout cast+transpose workers: Wout[256][50257] f32 -> WoutT[50304][256] bf16
        u16* tile = (u16*)smem;   // [64][66]
        const int r = tid >> 4, i = tid & 15;
        for (int tau = bid - 64; tau < 786*4; tau += 160){
            int ky = tau / 786;
            int nx = tau - ky*786;
            int n0 = nx*64, k0 = ky*64;
            #pragma unroll
            for (int jj = 0; jj < 4; ++jj){
                int n = n0 + i*4 + jj;
                float f = (n < VV) ? Wout[(size_t)(k0 + r)*VV + n] : 0.0f;
                tile[(i*4 + jj)*66 + r] = f2bf(f);
            }
            __syncthreads();
            {
                int kl = i*4;
                uint2 v;
                v.x = (uint32_t)tile[r*66 + kl+0] | ((uint32_t)tile[r*66 + kl+1] << 16);
                v.y = (uint32_t)tile[r*66 + kl+2] | ((uint32_t)tile[r*66 + kl+3] << 16);
                *(uint2*)(&WoutT[(size_t)(n0 + r)*256 + k0 + kl]) = v;
            }
            __syncthreads();
        }
        return;
    }

    const int g  = bid & 7;    // group (2 batches: 2g, 2g+1)
    const int rr = bid >> 3;   // 0..3 = L1 slice, 4..7 = L2 slice
    const int l  = tid & 63;
    const int wv = tid >> 6;   // 16 waves
    const int c  = l & 15;     // fragment column
    const int kb = (l >> 4) << 3;   // k sub-offset in 32-k slice
    const int b4 = l & 12;     // base lane of this unit's 4 gate-lanes
    uint32_t* h1y32 = (uint32_t*)h1y;
    uint32_t* h2b32 = (uint32_t*)h2b;

    if (rr < 4){
        // ========== L1: block owns units 64*r1..+63; wave wv owns units 64*r1+4wv..+3 x 4 gates
        const int r1 = rr;
        const int colg = (c&3)*HH + 64*r1 + 4*wv + (c>>2);
        short8 wf[8];
        #pragma unroll
        for (int kk = 0; kk < 8; ++kk){
            short8 s;
            #pragma unroll
            for (int j = 0; j < 8; ++j)
                s[j] = (short)f2bf(W1[(size_t)(HH + kk*32 + kb + j)*GG + colg]);
            wf[kk] = s;
        }
        u16*      hA   = (u16*)smem;     // [2][256] bf16
        uint32_t* hA32 = (uint32_t*)smem;
        float creg0 = 0.f, creg1 = 0.f;

        for (int t = 0; t < TT; ++t){
            float c0 = 0.f, c1 = 0.f;
            if (l < 16){
                c0 = G1t[((size_t)t*BB + 2*g + 0)*GG + colg];
                c1 = G1t[((size_t)t*BB + 2*g + 1)*GG + colg];
            }
            f32x4 acc = {c0, c1, 0.f, 0.f};
            f32x4 acc2 = {0.f, 0.f, 0.f, 0.f};
            if (t > 0){
                if (tid < 256){
                    int b = tid >> 7, p = tid & 127;
                    hA32[b*128 + p] = poll_pair(&h1y32[(((size_t)(t-1)*8 + g)*2 + b)*128 + p]);
                }
                __syncthreads();
                const u16* app = hA + (l & 1)*256 + kb;
                #pragma unroll
                for (int kk = 0; kk < 4; ++kk){
                    acc  = __builtin_amdgcn_mfma_f32_16x16x32_bf16(*(const short8*)(app + (2*kk  )*32), wf[2*kk  ], acc , 0, 0, 0);
                    acc2 = __builtin_amdgcn_mfma_f32_16x16x32_bf16(*(const short8*)(app + (2*kk+1)*32), wf[2*kk+1], acc2, 0, 0, 0);
                }
            }
            float v0 = acc[0] + acc2[0], v1 = acc[1] + acc2[1];
            // in-wave act: unit's 4 gates live on lanes b4..b4+3 (valid sources: lanes 0..15)
            float gi0=__shfl(v0,b4+0), gj0=__shfl(v0,b4+1), gf0=__shfl(v0,b4+2), go0=__shfl(v0,b4+3);
            float gi1=__shfl(v1,b4+0), gj1=__shfl(v1,b4+1), gf1=__shfl(v1,b4+2), go1=__shfl(v1,b4+3);
            float cn0 = creg0*sigm(gf0+1.f) + sigm(gi0)*tanha(gj0);
            float cn1 = creg1*sigm(gf1+1.f) + sigm(gi1)*tanha(gj1);
            float hn0 = tanha(cn0)*sigm(go0);
            float hn1 = tanha(cn1)*sigm(go1);
            creg0 = cn0; creg1 = cn1;
            uint32_t p0 = f2bf(hn0), p1 = f2bf(hn1);
            uint32_t q0 = (uint32_t)__shfl((int)p0, (l+4)&63);
            uint32_t q1 = (uint32_t)__shfl((int)p1, (l+4)&63);
            if (l == 0 || l == 8){
                uint32_t pi = 32*r1 + 2*wv + (l>>3);
                st32_coh(&h1y32[(((size_t)t*8 + g)*2 + 0)*128 + pi], p0 | (q0<<16));
                st32_coh(&h1y32[(((size_t)t*8 + g)*2 + 1)*128 + pi], p1 | (q1<<16));
            }
            __syncthreads();   // protects hA reuse; parks waves together (r7 lesson)
        }
    } else {
        // ========== L2: block owns units 64*r2..+63; wave wv owns 4 units x 4 gates, full K=512
        const int r2 = rr - 4;
        const int colg = (c&3)*HH + 64*r2 + 4*wv + (c>>2);
        short8 wf[16];
        #pragma unroll
        for (int kk = 0; kk < 16; ++kk){
            short8 s;
            #pragma unroll
            for (int j = 0; j < 8; ++j)
                s[j] = (short)f2bf(W2[(size_t)(kk*32 + kb + j)*GG + colg]);
            wf[kk] = s;
        }
        float bvg = b2[colg];
        u16*      uB   = (u16*)smem;     // [2][512] bf16: [b][h1(256);h2(256)]
        uint32_t* uB32 = (uint32_t*)smem;
        float creg0 = 0.f, creg1 = 0.f;

        for (int tt = 0; tt < TT; ++tt){
            if (tid < 512){
                int b = tid >> 8, q = tid & 255;   // q<128: h1 pair q; q>=128: h2 pair q-128
                uint32_t v;
                if (q < 128)
                    v = poll_pair(&h1y32[(((size_t)tt*8 + g)*2 + b)*128 + q]);
                else if (tt > 0)
                    v = poll_pair(&h2b32[((size_t)(2*g + b)*TT + (tt-1))*128 + (q - 128)]);
                else
                    v = 0;
                uB32[b*256 + q] = v;
            }
            __syncthreads();
            f32x4 acc  = {0.f, 0.f, 0.f, 0.f};
            f32x4 acc2 = {0.f, 0.f, 0.f, 0.f};
            const u16* app = uB + (l & 1)*512 + kb;
            #pragma unroll
            for (int kk = 0; kk < 8; ++kk){
                acc  = __builtin_amdgcn_mfma_f32_16x16x32_bf16(*(const short8*)(app + (2*kk  )*32), wf[2*kk  ], acc , 0, 0, 0);
                acc2 = __builtin_amdgcn_mfma_f32_16x16x32_bf16(*(const short8*)(app + (2*kk+1)*32), wf[2*kk+1], acc2, 0, 0, 0);
            }
            float v0 = acc[0] + acc2[0] + bvg, v1 = acc[1] + acc2[1] + bvg;
            float gi0=__shfl(v0,b4+0), gj0=__shfl(v0,b4+1), gf0=__shfl(v0,b4+2), go0=__shfl(v0,b4+3);
            float gi1=__shfl(v1,b4+0), gj1=__shfl(v1,b4+1), gf1=__shfl(v1,b4+2), go1=__shfl(v1,b4+3);
            float cn0 = creg0*sigm(gf0+1.f) + sigm(gi0)*tanha(gj0);
            float cn1 = creg1*sigm(gf1+1.f) + sigm(gi1)*tanha(gj1);
            float hn0 = tanha(cn0)*sigm(go0);
            float hn1 = tanha(cn1)*sigm(go1);
            creg0 = cn0; creg1 = cn1;
            uint32_t p0 = f2bf(hn0), p1 = f2bf(hn1);
            uint32_t q0 = (uint32_t)__shfl((int)p0, (l+4)&63);
            uint32_t q1 = (uint32_t)__shfl((int)p1, (l+4)&63);
            if (l == 0 || l == 8){
                uint32_t pi = 32*r2 + 2*wv + (l>>3);
                st32_coh(&h2b32[((size_t)(2*g + 0)*TT + tt)*128 + pi], p0 | (q0<<16));
                st32_coh(&h2b32[((size_t)(2*g + 1)*TT + tt)*128 + pi], p1 | (q1<<16));
            }
            __syncthreads();   // protects uB reuse (r7 lesson)
        }
    }
}

// ---------------- out = h2b[4096,256] @ WoutT^T + bout
// 128x128 tile, BK=64 SINGLE-buffer gload_lds (36KB LDS incl. padded epilogue -> 4 blocks/CU).
__global__ __launch_bounds__(256, 4) void out_gemm(const u16* __restrict__ A, const u16* __restrict__ Bt,
                                                   const float* __restrict__ bout, float* __restrict__ out){
    __shared__ __align__(16) char smem[36864];
    u16* ldsA = (u16*)smem;                      // [128 rows][64 k] bf16, XOR-swizzled
    u16* ldsB = (u16*)(smem + 16384);
    float* ldsF = (float*)smem;                  // epilogue reuse, stride 132 (bank-conflict-free)
    const int bid = blockIdx.x;
    const int x   = bid & 7;
    const int wgl = bid >> 3;
    const int mb  = x*4 + (wgl & 3);
    const int nb  = wgl >> 2;
    const int m0 = mb*128, n0 = nb*128;
    const int tid = threadIdx.x;
    const int l = tid & 63;
    const int wv = tid >> 6;
    const int wm = wv >> 1, wn = wv & 1;
    const int lr = l & 15, lh = l >> 4;

    f32x4 acc[4][4];
    #pragma unroll
    for (int mf = 0; mf < 4; ++mf)
        #pragma unroll
        for (int nf = 0; nf < 4; ++nf) acc[mf][nf] = (f32x4){0.f,0.f,0.f,0.f};

    #pragma unroll
    for (int ks = 0; ks < 4; ++ks){
        #pragma unroll
        for (int j = 0; j < 4; ++j){
            int f = j*256 + tid;
            int row = f >> 3;
            int kps = (f & 7) ^ (row & 7);
            gl_lds16(A  + (size_t)(m0+row)*256 + ks*64 + kps*8, (char*)ldsA + f*16);
            gl_lds16(Bt + (size_t)(n0+row)*256 + ks*64 + kps*8, (char*)ldsB + f*16);
        }
        __syncthreads();
        #pragma unroll
        for (int ksub = 0; ksub < 2; ++ksub){
            short8 af[4], bf[4];
            const int kp = ksub*4 + lh;
            #pragma unroll
            for (int mf = 0; mf < 4; ++mf){
                int row = wm*64 + mf*16 + lr;
                af[mf] = *(const short8*)((const char*)ldsA + row*128 + ((kp ^ (row&7)) << 4));
            }
            #pragma unroll
            for (int nf = 0; nf < 4; ++nf){
                int row = wn*64 + nf*16 + lr;
                bf[nf] = *(const short8*)((const char*)ldsB + row*128 + ((kp ^ (row&7)) << 4));
            }
            #pragma unroll
            for (int mf = 0; mf < 4; ++mf)
                #pragma unroll
                for (int nf = 0; nf < 4; ++nf)
                    acc[mf][nf] = __builtin_amdgcn_mfma_f32_16x16x32_bf16(af[mf], bf[nf], acc[mf][nf], 0, 0, 0);
        }
        __syncthreads();
    }

    for (int h = 0; h < 2; ++h){
        if (wm == h){
            #pragma unroll
            for (int nf = 0; nf < 4; ++nf){
                int col = wn*64 + nf*16 + lr;
                int gcol = n0 + col;
                float bb2 = (gcol < VV) ? bout[gcol] : 0.0f;
                #pragma unroll
                for (int mf = 0; mf < 4; ++mf)
                    #pragma unroll
                    for (int r = 0; r < 4; ++r)
                        ldsF[(mf*16 + lh*4 + r)*132 + col] = acc[mf][nf][r] + bb2;
            }
        }
        __syncthreads();
        #pragma unroll
        for (int j = 0; j < 8; ++j){
            int f = j*256 + tid;
            int row = f >> 5;
            int c4 = (f & 31)*4;
            int gcol = n0 + c4;
            f32x4 v = *(const f32x4*)(ldsF + row*132 + c4);
            int grow = m0 + h*64 + row;
            if (gcol + 3 < VV){
                *(f32x4*)(&out[(size_t)grow*VV + gcol]) = v;
            } else {
                #pragma unroll
                for (int e = 0; e < 4; ++e)
                    if (gcol + e < VV) out[(size_t)grow*VV + gcol + e] = v[e];
            }
        }
        __syncthreads();
    }
}

extern "C" void kernel_launch(void* const* d_in, const int* in_sizes, int n_in,
                              void* d_out, int out_size, void* d_ws, size_t ws_size,
                              hipStream_t stream) {
    const int*   tok  = (const int*)d_in[0];
    const float* emb  = (const float*)d_in[1];
    const float* W1   = (const float*)d_in[2];
    const float* b1   = (const float*)d_in[3];
    const float* W2   = (const float*)d_in[4];
    const float* b2   = (const float*)d_in[5];
    const float* Wout = (const float*)d_in[6];
    const float* bout = (const float*)d_in[7];
    float* out = (float*)d_out;
    char* ws = (char*)d_ws;

    u16*   h1y   = (u16*)  (ws);                        //  2,097,152 B  [T][8][2][256]
    u16*   h2b   = (u16*)  (ws + 2097152);              //  2,097,152 B  [16][T][256]
    float* G1t   = (float*)(ws + 4194304);              // 16,777,216 B  [T*16][1024]
    u16*   WoutT = (u16*)  (ws + 4194304 + 16777216);   // 25,755,648 B  [50304][256]

    hipMemsetAsync(ws, 0xFF, 4194304, stream);   // sentinel-fill h1y + h2b (replay-safe)
    g1_kernel<<<dim3(64, 16), 256, 0, stream>>>(tok, emb, W1, b1, G1t);
    persist_kernel<<<224, 1024, 0, stream>>>(G1t, W1, W2, b2, Wout, WoutT, h1y, h2b);
    out_gemm<<<12576, 256, 0, stream>>>(h2b, WoutT, bout, out);
}

// Round 16
// 755.222 us; speedup vs baseline: 1.4323x; 1.4323x over previous
//
#include <hip/hip_runtime.h>
#include <hip/hip_bf16.h>
#include <stdint.h>

#define BB 16
#define TT 256
#define HH 256
#define EE 256
#define GG 1024      // 4*H
#define VV 50257
#define NN 4096      // B*T

typedef unsigned short u16;
typedef __attribute__((ext_vector_type(8))) short short8;
typedef __attribute__((ext_vector_type(4))) float f32x4;

__device__ __forceinline__ float sigm(float x){
    float e = __builtin_amdgcn_exp2f(fminf(-x*1.44269504f, 60.0f));
    return 1.0f/(1.0f+e);
}
__device__ __forceinline__ float tanha(float x){
    float e = __builtin_amdgcn_exp2f(fminf(x*2.885390082f, 60.0f));
    return (e-1.0f)/(e+1.0f);
}
__device__ __forceinline__ u16 f2bf(float f){
    uint32_t u = __float_as_uint(f);
    u = (u + 0x7FFFu + ((u>>16)&1u)) >> 16;
    return (u16)u;
}
// agent-scope (device-coherent) ops; data-as-flag polling. Sentinel bf16 = 0xFFFF (NaN, never produced).
__device__ __forceinline__ void st32_coh(uint32_t* p, uint32_t v){
    __hip_atomic_store(p, v, __ATOMIC_RELAXED, __HIP_MEMORY_SCOPE_AGENT);
}
__device__ __forceinline__ uint32_t poll_pair(const uint32_t* p){
    uint32_t v = __hip_atomic_load(p, __ATOMIC_RELAXED, __HIP_MEMORY_SCOPE_AGENT);
    while ((v & 0xFFFFu) == 0xFFFFu || (v >> 16) == 0xFFFFu){
        __builtin_amdgcn_s_sleep(1);
        v = __hip_atomic_load(p, __ATOMIC_RELAXED, __HIP_MEMORY_SCOPE_AGENT);
    }
    return v;
}
__device__ __forceinline__ void gl_lds16(const void* g, void* s){
    __builtin_amdgcn_global_load_lds((const __attribute__((address_space(1))) unsigned int*)g,
                                     (__attribute__((address_space(3))) unsigned int*)s, 16, 0, 0);
}

// ---------------- G1t[(t*16+b)][g] = b1[g] + sum_e emb[tok[b*T+t]][e] * W1[e][g]
__global__ __launch_bounds__(256) void g1_kernel(const int* __restrict__ tok, const float* __restrict__ emb,
                                                 const float* __restrict__ W1, const float* __restrict__ b1,
                                                 float* __restrict__ G1t){
    __shared__ float xs[64*64];
    __shared__ float wsm[64*64];
    int n0 = blockIdx.x * 64;
    int g0 = blockIdx.y * 64;
    int tid = threadIdx.x;
    int sl = tid & 63;
    int kk = (tid >> 6) * 16;
    int mytok = tok[n0 + sl];
    float acc[4][4] = {};
    int ni = tid & 15, gi = tid >> 4;
    for (int kc = 0; kc < 4; ++kc){
        int k0 = kc*64;
        __syncthreads();
        #pragma unroll
        for (int i4 = 0; i4 < 4; ++i4){
            float4 xv = *(const float4*)(&emb[(size_t)mytok*EE + k0 + kk + i4*4]);
            xs[(kk+i4*4+0)*64 + sl] = xv.x;
            xs[(kk+i4*4+1)*64 + sl] = xv.y;
            xs[(kk+i4*4+2)*64 + sl] = xv.z;
            xs[(kk+i4*4+3)*64 + sl] = xv.w;
        }
        #pragma unroll
        for (int i = 0; i < 16; ++i){
            wsm[(kk+i)*64 + sl] = W1[(size_t)(k0+kk+i)*GG + g0 + sl];
        }
        __syncthreads();
        for (int k = 0; k < 64; ++k){
            float4 av = *(const float4*)(&xs[k*64 + ni*4]);
            float4 bv = *(const float4*)(&wsm[k*64 + gi*4]);
            float a_[4] = {av.x, av.y, av.z, av.w};
            float b_[4] = {bv.x, bv.y, bv.z, bv.w};
            #pragma unroll
            for (int i = 0; i < 4; ++i)
                #pragma unroll
                for (int j = 0; j < 4; ++j)
                    acc[i][j] += a_[i]*b_[j];
        }
    }
    #pragma unroll
    for (int i = 0; i < 4; ++i){
        int n = n0 + ni*4 + i;
        int b = n >> 8;
        int tt_ = n & 255;
        float4 o;
        o.x = acc[i][0] + b1[g0+gi*4+0];
        o.y = acc[i][1] + b1[g0+gi*4+1];
        o.z = acc[i][2] + b1[g0+gi*4+2];
        o.w = acc[i][3] + b1[g0+gi*4+3];
        *(float4*)(&G1t[(size_t)(tt_*16 + b)*GG + g0 + gi*4]) = o;
    }
}

// ---------------- persistent: 96 recurrence blocks (8 groups x (4 L1 + 8 L2)), 128 transpose workers
// h1y: [T][8grp][2b][256u] bf16 exchange (sentinel 0xFFFF), packed u32 stores
// h2b: [16b][T][256u] bf16 — BOTH the L2 exchange buffer and out_gemm's A matrix
__global__ __launch_bounds__(1024) void persist_kernel(
        const float* __restrict__ G1t, const float* __restrict__ W1,
        const float* __restrict__ W2, const float* __restrict__ b2,
        const float* __restrict__ Wout, u16* __restrict__ WoutT,
        u16* __restrict__ h1y, u16* __restrict__ h2b){
    __shared__ __align__(16) char smem[12288];
    const int bid = blockIdx.x;
    const int tid = threadIdx.x;

    if (bid >= 96){
        // ---- Wout cast+transpose workers: Wout[256][50257] f32 -> WoutT[50304][256] bf16
        u16* tile = (u16*)smem;   // [64][66]
        const int r = tid >> 4, i = tid & 15;
        for (int tau = bid - 96; tau < 786*4; tau += 128){
            int ky = tau / 786;
            int nx = tau - ky*786;
            int n0 = nx*64, k0 = ky*64;
            #pragma unroll
            for (int jj = 0; jj < 4; ++jj){
                int n = n0 + i*4 + jj;
                float f = (n < VV) ? Wout[(size_t)(k0 + r)*VV + n] : 0.0f;
                tile[(i*4 + jj)*66 + r] = f2bf(f);
            }
            __syncthreads();
            {
                int kl = i*4;
                uint2 v;
                v.x = (uint32_t)tile[r*66 + kl+0] | ((uint32_t)tile[r*66 + kl+1] << 16);
                v.y = (uint32_t)tile[r*66 + kl+2] | ((uint32_t)tile[r*66 + kl+3] << 16);
                *(uint2*)(&WoutT[(size_t)(n0 + r)*256 + k0 + kl]) = v;
            }
            __syncthreads();
        }
        return;
    }

    const int g  = bid & 7;    // group (2 batches: 2g, 2g+1); group's blocks share bid%8 (same XCD)
    const int rr = bid >> 3;   // 0..3 = L1 slice, 4..11 = L2 slice
    const int l  = tid & 63;
    const int wv = tid >> 6;
    uint32_t* h1y32 = (uint32_t*)h1y;
    uint32_t* h2b32 = (uint32_t*)h2b;

    if (rr < 4){
        // ========== L1: gates[2, 256cols] = G1t + h1_{t-1} @ W1rec   (block owns units 64*r1..+64)
        const int r1 = rr;
        const int gate = wv >> 2, usub = wv & 3;
        const int colw = gate*HH + 64*r1 + 16*usub;
        short8 wf[8];
        {
            const int col = colw + (l & 15);
            const int kb = (l >> 4) << 3;
            #pragma unroll
            for (int kk = 0; kk < 8; ++kk){
                short8 s;
                #pragma unroll
                for (int j = 0; j < 8; ++j)
                    s[j] = (short)f2bf(W1[(size_t)(HH + kk*32 + kb + j)*GG + col]);
                wf[kk] = s;
            }
        }
        u16*      hA   = (u16*)smem;             // [2][256] bf16
        uint32_t* hA32 = (uint32_t*)smem;
        float*    gm   = (float*)(smem + 1024);  // [4gate][64u][2b] f32
        const int ab = tid >> 5, ap_ = tid & 31; // act map: tid<64 -> batch, unit-pair
        float creg0 = 0.f, creg1 = 0.f;

        for (int t = 0; t < TT; ++t){
            float c0 = 0.f, c1 = 0.f;
            if (l < 16){
                c0 = G1t[((size_t)t*BB + 2*g + 0)*GG + colw + l];
                c1 = G1t[((size_t)t*BB + 2*g + 1)*GG + colw + l];
            }
            f32x4 acc = {c0, c1, 0.f, 0.f};
            if (t > 0){
                if (tid < 256){
                    int b = tid >> 7, p = tid & 127;
                    hA32[b*128 + p] = poll_pair(&h1y32[(((size_t)(t-1)*8 + g)*2 + b)*128 + p]);
                }
                __syncthreads();
                const u16* app = hA + (l & 1)*256 + ((l >> 4) << 3);
                f32x4 acc2 = {0.f, 0.f, 0.f, 0.f};
                #pragma unroll
                for (int kk = 0; kk < 4; ++kk){
                    acc  = __builtin_amdgcn_mfma_f32_16x16x32_bf16(*(const short8*)(app + (2*kk  )*32), wf[2*kk  ], acc , 0, 0, 0);
                    acc2 = __builtin_amdgcn_mfma_f32_16x16x32_bf16(*(const short8*)(app + (2*kk+1)*32), wf[2*kk+1], acc2, 0, 0, 0);
                }
                acc[0] += acc2[0];
                acc[1] += acc2[1];
            }
            if (l < 16){
                gm[(gate*64 + usub*16 + l)*2 + 0] = acc[0];
                gm[(gate*64 + usub*16 + l)*2 + 1] = acc[1];
            }
            __syncthreads();
            if (tid < 64){
                int u0 = 2*ap_, u1 = 2*ap_ + 1;
                float gi0 = gm[(0*64 + u0)*2 + ab], gi1 = gm[(0*64 + u1)*2 + ab];
                float gj0 = gm[(1*64 + u0)*2 + ab], gj1 = gm[(1*64 + u1)*2 + ab];
                float gf0 = gm[(2*64 + u0)*2 + ab], gf1 = gm[(2*64 + u1)*2 + ab];
                float go0 = gm[(3*64 + u0)*2 + ab], go1 = gm[(3*64 + u1)*2 + ab];
                float cn0 = creg0 * sigm(gf0 + 1.0f) + sigm(gi0)*tanha(gj0);
                float cn1 = creg1 * sigm(gf1 + 1.0f) + sigm(gi1)*tanha(gj1);
                float hn0 = tanha(cn0)*sigm(go0);
                float hn1 = tanha(cn1)*sigm(go1);
                creg0 = cn0; creg1 = cn1;
                uint32_t pk = (uint32_t)f2bf(hn0) | ((uint32_t)f2bf(hn1) << 16);
                st32_coh(&h1y32[(((size_t)t*8 + g)*2 + ab)*128 + 32*r1 + ap_], pk);
            }
            __syncthreads();   // trailing barrier: parks non-act waves (r7 post-mortem: removing it hurts)
        }
    } else {
        // ========== L2: gates[2, 128cols] = b2 + [h1_t ; h2_{t-1}] @ W2   (block owns units 32*r2..+32)
        const int r2 = rr - 4;
        const int nt = wv >> 1, kh = wv & 1;
        const int gate = nt >> 1, usub = nt & 1;
        const int colw = gate*HH + 32*r2 + 16*usub;
        short8 wf[8];
        {
            const int col = colw + (l & 15);
            const int kb = (l >> 4) << 3;
            #pragma unroll
            for (int kk = 0; kk < 8; ++kk){
                short8 s;
                #pragma unroll
                for (int j = 0; j < 8; ++j)
                    s[j] = (short)f2bf(W2[(size_t)(kh*256 + kk*32 + kb + j)*GG + col]);
                wf[kk] = s;
            }
        }
        u16*      uB   = (u16*)smem;             // [2][512] bf16: [b][h1(256);h2(256)]
        uint32_t* uB32 = (uint32_t*)smem;
        float*    gm   = (float*)(smem + 2048);  // [4gate][32u][2b][2kh] f32
        const int ab = tid >> 4, ap_ = tid & 15; // act map: tid<32
        float creg0 = 0.f, creg1 = 0.f;
        float bvs[4][2];
        if (tid < 32){
            #pragma unroll
            for (int gg = 0; gg < 4; ++gg){
                bvs[gg][0] = b2[gg*HH + 32*r2 + 2*ap_];
                bvs[gg][1] = b2[gg*HH + 32*r2 + 2*ap_ + 1];
            }
        }

        for (int tt = 0; tt < TT; ++tt){
            if (tid < 512){
                int b = tid >> 8, q = tid & 255;   // q<128: h1 pair q; q>=128: h2 pair q-128
                uint32_t v;
                if (q < 128)
                    v = poll_pair(&h1y32[(((size_t)tt*8 + g)*2 + b)*128 + q]);
                else if (tt > 0)
                    v = poll_pair(&h2b32[((size_t)(2*g + b)*TT + (tt-1))*128 + (q - 128)]);
                else
                    v = 0;
                uB32[b*256 + q] = v;
            }
            __syncthreads();
            f32x4 acc = {0.f, 0.f, 0.f, 0.f};
            f32x4 acc2 = {0.f, 0.f, 0.f, 0.f};
            const u16* app = uB + (l & 1)*512 + kh*256 + ((l >> 4) << 3);
            #pragma unroll
            for (int kk = 0; kk < 4; ++kk){
                acc  = __builtin_amdgcn_mfma_f32_16x16x32_bf16(*(const short8*)(app + (2*kk  )*32), wf[2*kk  ], acc , 0, 0, 0);
                acc2 = __builtin_amdgcn_mfma_f32_16x16x32_bf16(*(const short8*)(app + (2*kk+1)*32), wf[2*kk+1], acc2, 0, 0, 0);
            }
            acc[0] += acc2[0];
            acc[1] += acc2[1];
            if (l < 16){
                gm[((gate*32 + usub*16 + l)*2 + 0)*2 + kh] = acc[0];
                gm[((gate*32 + usub*16 + l)*2 + 1)*2 + kh] = acc[1];
            }
            __syncthreads();
            if (tid < 32){
                int u0 = 2*ap_, u1 = 2*ap_ + 1;
                float gi0 = gm[((0*32 + u0)*2 + ab)*2 + 0] + gm[((0*32 + u0)*2 + ab)*2 + 1] + bvs[0][0];
                float gi1 = gm[((0*32 + u1)*2 + ab)*2 + 0] + gm[((0*32 + u1)*2 + ab)*2 + 1] + bvs[0][1];
                float gj0 = gm[((1*32 + u0)*2 + ab)*2 + 0] + gm[((1*32 + u0)*2 + ab)*2 + 1] + bvs[1][0];
                float gj1 = gm[((1*32 + u1)*2 + ab)*2 + 0] + gm[((1*32 + u1)*2 + ab)*2 + 1] + bvs[1][1];
                float gf0 = gm[((2*32 + u0)*2 + ab)*2 + 0] + gm[((2*32 + u0)*2 + ab)*2 + 1] + bvs[2][0];
                float gf1 = gm[((2*32 + u1)*2 + ab)*2 + 0] + gm[((2*32 + u1)*2 + ab)*2 + 1] + bvs[2][1];
                float go0 = gm[((3*32 + u0)*2 + ab)*2 + 0] + gm[((3*32 + u0)*2 + ab)*2 + 1] + bvs[3][0];
                float go1 = gm[((3*32 + u1)*2 + ab)*2 + 0] + gm[((3*32 + u1)*2 + ab)*2 + 1] + bvs[3][1];
                float cn0 = creg0 * sigm(gf0 + 1.0f) + sigm(gi0)*tanha(gj0);
                float cn1 = creg1 * sigm(gf1 + 1.0f) + sigm(gi1)*tanha(gj1);
                float hn0 = tanha(cn0)*sigm(go0);
                float hn1 = tanha(cn1)*sigm(go1);
                creg0 = cn0; creg1 = cn1;
                uint32_t pk = (uint32_t)f2bf(hn0) | ((uint32_t)f2bf(hn1) << 16);
                st32_coh(&h2b32[((size_t)(2*g + ab)*TT + tt)*128 + 16*r2 + ap_], pk);
            }
            __syncthreads();   // trailing barrier (see r7 post-mortem)
        }
    }
}

// ---------------- out = h2b[4096,256] @ WoutT^T + bout
// 128x128 tile, BK=64 SINGLE-buffer gload_lds (36KB LDS -> 4 blocks/CU).
// Epilogue: nontemporal f32x4 stores — each wave covers a contiguous 1KB span (full 64B lines,
// no RMW; distinct from r6's scalar-NT failure) and keeps the 823MB write stream out of L2.
__global__ __launch_bounds__(256, 4) void out_gemm(const u16* __restrict__ A, const u16* __restrict__ Bt,
                                                   const float* __restrict__ bout, float* __restrict__ out){
    __shared__ __align__(16) char smem[36864];
    u16* ldsA = (u16*)smem;                      // [128 rows][64 k] bf16, XOR-swizzled
    u16* ldsB = (u16*)(smem + 16384);
    float* ldsF = (float*)smem;                  // epilogue reuse, stride 132 (bank-conflict-free)
    const int bid = blockIdx.x;
    const int x   = bid & 7;
    const int wgl = bid >> 3;
    const int mb  = x*4 + (wgl & 3);
    const int nb  = wgl >> 2;
    const int m0 = mb*128, n0 = nb*128;
    const int tid = threadIdx.x;
    const int l = tid & 63;
    const int wv = tid >> 6;
    const int wm = wv >> 1, wn = wv & 1;
    const int lr = l & 15, lh = l >> 4;

    f32x4 acc[4][4];
    #pragma unroll
    for (int mf = 0; mf < 4; ++mf)
        #pragma unroll
        for (int nf = 0; nf < 4; ++nf) acc[mf][nf] = (f32x4){0.f,0.f,0.f,0.f};

    #pragma unroll
    for (int ks = 0; ks < 4; ++ks){
        #pragma unroll
        for (int j = 0; j < 4; ++j){
            int f = j*256 + tid;
            int row = f >> 3;
            int kps = (f & 7) ^ (row & 7);
            gl_lds16(A  + (size_t)(m0+row)*256 + ks*64 + kps*8, (char*)ldsA + f*16);
            gl_lds16(Bt + (size_t)(n0+row)*256 + ks*64 + kps*8, (char*)ldsB + f*16);
        }
        __syncthreads();
        #pragma unroll
        for (int ksub = 0; ksub < 2; ++ksub){
            short8 af[4], bf[4];
            const int kp = ksub*4 + lh;
            #pragma unroll
            for (int mf = 0; mf < 4; ++mf){
                int row = wm*64 + mf*16 + lr;
                af[mf] = *(const short8*)((const char*)ldsA + row*128 + ((kp ^ (row&7)) << 4));
            }
            #pragma unroll
            for (int nf = 0; nf < 4; ++nf){
                int row = wn*64 + nf*16 + lr;
                bf[nf] = *(const short8*)((const char*)ldsB + row*128 + ((kp ^ (row&7)) << 4));
            }
            #pragma unroll
            for (int mf = 0; mf < 4; ++mf)
                #pragma unroll
                for (int nf = 0; nf < 4; ++nf)
                    acc[mf][nf] = __builtin_amdgcn_mfma_f32_16x16x32_bf16(af[mf], bf[nf], acc[mf][nf], 0, 0, 0);
        }
        __syncthreads();
    }

    for (int h = 0; h < 2; ++h){
        if (wm == h){
            #pragma unroll
            for (int nf = 0; nf < 4; ++nf){
                int col = wn*64 + nf*16 + lr;
                int gcol = n0 + col;
                float bb2 = (gcol < VV) ? bout[gcol] : 0.0f;
                #pragma unroll
                for (int mf = 0; mf < 4; ++mf)
                    #pragma unroll
                    for (int r = 0; r < 4; ++r)
                        ldsF[(mf*16 + lh*4 + r)*132 + col] = acc[mf][nf][r] + bb2;
            }
        }
        __syncthreads();
        #pragma unroll
        for (int j = 0; j < 8; ++j){
            int f = j*256 + tid;
            int row = f >> 5;
            int c4 = (f & 31)*4;
            int gcol = n0 + c4;
            f32x4 v = *(const f32x4*)(ldsF + row*132 + c4);
            int grow = m0 + h*64 + row;
            if (gcol + 3 < VV){
                __builtin_nontemporal_store(v, (f32x4*)&out[(size_t)grow*VV + gcol]);
            } else {
                #pragma unroll
                for (int e = 0; e < 4; ++e)
                    if (gcol + e < VV) out[(size_t)grow*VV + gcol + e] = v[e];
            }
        }
        __syncthreads();
    }
}

extern "C" void kernel_launch(void* const* d_in, const int* in_sizes, int n_in,
                              void* d_out, int out_size, void* d_ws, size_t ws_size,
                              hipStream_t stream) {
    const int*   tok  = (const int*)d_in[0];
    const float* emb  = (const float*)d_in[1];
    const float* W1   = (const float*)d_in[2];
    const float* b1   = (const float*)d_in[3];
    const float* W2   = (const float*)d_in[4];
    const float* b2   = (const float*)d_in[5];
    const float* Wout = (const float*)d_in[6];
    const float* bout = (const float*)d_in[7];
    float* out = (float*)d_out;
    char* ws = (char*)d_ws;

    u16*   h1y   = (u16*)  (ws);                        //  2,097,152 B  [T][8][2][256]
    u16*   h2b   = (u16*)  (ws + 2097152);              //  2,097,152 B  [16][T][256]
    float* G1t   = (float*)(ws + 4194304);              // 16,777,216 B  [T*16][1024]
    u16*   WoutT = (u16*)  (ws + 4194304 + 16777216);   // 25,755,648 B  [50304][256]

    hipMemsetAsync(ws, 0xFF, 4194304, stream);   // sentinel-fill h1y + h2b (replay-safe)
    g1_kernel<<<dim3(64, 16), 256, 0, stream>>>(tok, emb, W1, b1, G1t);
    persist_kernel<<<224, 1024, 0, stream>>>(G1t, W1, W2, b2, Wout, WoutT, h1y, h2b);
    out_gemm<<<12576, 256, 0, stream>>>(h2b, WoutT, bout, out);
}